// Round 1
// baseline (360.921 us; speedup 1.0000x reference)
//
#include <hip/hip_runtime.h>
#include <math.h>

#define NB   16
#define NQ   75
#define NN   (NB*NQ)    // 1200
#define CC   640
#define HW   25
#define MS   125        // n_way*hw
#define CK   320        // c per chunk
#define CK4  (CK/4)     // 80
#define EPSF 1e-8f

// ---------------- A1: support mean over k_shot + transpose to [b][w][j][c] ---
__global__ __launch_bounds__(256) void kA1(const float* __restrict__ sxf,
                                           float* __restrict__ supm) {
  const int blk = blockIdx.x;            // b*5+w, 0..79
  const int tid = threadIdx.x;
  __shared__ __align__(16) float mch[CK4 * 100];   // [c4][j][4]
  const float* base = sxf + (size_t)blk * 5 * 16000;  // (b*25+w*5)*16000
  float* outb = supm + (size_t)blk * 16000;

  for (int ch = 0; ch < 2; ++ch) {
    __syncthreads();
    const int fbase = ch * 8000;
    for (int f0 = tid * 4; f0 < 8000; f0 += 1024) {
      float4 a = *(const float4*)(base + fbase + f0);
      float4 b1 = *(const float4*)(base + 16000 + fbase + f0);
      float4 c1 = *(const float4*)(base + 32000 + fbase + f0);
      float4 d1 = *(const float4*)(base + 48000 + fbase + f0);
      float4 e1 = *(const float4*)(base + 64000 + fbase + f0);
      float v[4];
      v[0] = (a.x + b1.x + c1.x + d1.x + e1.x) * 0.2f;
      v[1] = (a.y + b1.y + c1.y + d1.y + e1.y) * 0.2f;
      v[2] = (a.z + b1.z + c1.z + d1.z + e1.z) * 0.2f;
      v[3] = (a.w + b1.w + c1.w + d1.w + e1.w) * 0.2f;
#pragma unroll
      for (int u = 0; u < 4; ++u) {
        int f = f0 + u;
        int j = f % 25, cl = f / 25;
        mch[(cl >> 2) * 100 + j * 4 + (cl & 3)] = v[u];
      }
    }
    __syncthreads();
    for (int g = tid; g < 8000; g += 256) {
      int j = g / 320, cl = g % 320;
      outb[j * 640 + ch * 320 + cl] = mch[(cl >> 2) * 100 + j * 4 + (cl & 3)];
    }
  }
}

// ---------------- A2: L2-normalize each 640-row of supm in place -------------
__global__ __launch_bounds__(256) void kA2(float* __restrict__ supm) {
  const int r = blockIdx.x * 4 + (threadIdx.x >> 6);  // 0..1999
  const int lane = threadIdx.x & 63;
  float* row = supm + (size_t)r * 640;
  float4 v0 = *(const float4*)(row + lane * 4);
  float4 v1 = *(const float4*)(row + 256 + lane * 4);
  float4 v2 = {0.f, 0.f, 0.f, 0.f};
  if (lane < 32) v2 = *(const float4*)(row + 512 + lane * 4);
  float ssq = v0.x*v0.x + v0.y*v0.y + v0.z*v0.z + v0.w*v0.w
            + v1.x*v1.x + v1.y*v1.y + v1.z*v1.z + v1.w*v1.w
            + v2.x*v2.x + v2.y*v2.y + v2.z*v2.z + v2.w*v2.w;
#pragma unroll
  for (int d = 32; d; d >>= 1) ssq += __shfl_xor(ssq, d);
  const float rinv = 1.f / (sqrtf(ssq) + EPSF);
  v0.x *= rinv; v0.y *= rinv; v0.z *= rinv; v0.w *= rinv;
  v1.x *= rinv; v1.y *= rinv; v1.z *= rinv; v1.w *= rinv;
  *(float4*)(row + lane * 4) = v0;
  *(float4*)(row + 256 + lane * 4) = v1;
  if (lane < 32) {
    v2.x *= rinv; v2.y *= rinv; v2.z *= rinv; v2.w *= rinv;
    *(float4*)(row + 512 + lane * 4) = v2;
  }
}

// ---------------- C: fused per-n GEMM + softmax + Katz + loss ----------------
__global__ __launch_bounds__(256) void kC(const float* __restrict__ qxf,
                                          const int* __restrict__ qy,
                                          const float* __restrict__ supt,
                                          float* __restrict__ out) {
  const int n = blockIdx.x;              // 0..1199
  const int b = n / 75;
  const int tid = threadIdx.x;
  __shared__ __align__(16) float qch[8000];   // [c4][i][4]; reused for Tsq/Tqs/B
  __shared__ float S[25 * 125];
  __shared__ float nsq[25], rinv[25], rhs[25], xv[25], Pk[5];

  const float* qb = qxf + (size_t)n * 16000;
  const float* supb = supt + (size_t)b * 80000;

  if (tid < 25) nsq[tid] = 0.f;
  if (tid < 5) Pk[tid] = 0.f;

  const int s = tid % 125;
  const int half = tid / 125;            // 0,1 compute; 2 = idle in GEMM
  const int i0 = half * 13;
  const int ni = (half == 0) ? 13 : ((half == 1) ? 12 : 0);
  float acc[13];
#pragma unroll
  for (int r = 0; r < 13; ++r) acc[r] = 0.f;
  const float* srow = supb + s * 640;

  for (int ch = 0; ch < 2; ++ch) {
    __syncthreads();                      // qch free to overwrite (also covers init)
    for (int f0 = tid * 4; f0 < 8000; f0 += 1024) {
      float4 v = *(const float4*)(qb + ch * 8000 + f0);
#pragma unroll
      for (int u = 0; u < 4; ++u) {
        int f = f0 + u;
        int i = f % 25, cl = f / 25;
        qch[(cl >> 2) * 100 + i * 4 + (cl & 3)] = ((const float*)&v)[u];
      }
    }
    __syncthreads();
    {   // query norm^2 partial: 8 c-groups x 25 i
      int i = tid & 31, cg = tid >> 5;
      if (i < 25) {
        float p = 0.f;
        for (int cc = 0; cc < 40; ++cc) {
          int cl = cg * 40 + cc;
          float q = qch[(cl >> 2) * 100 + i * 4 + (cl & 3)];
          p += q * q;
        }
        atomicAdd(&nsq[i], p);
      }
    }
    if (half < 2) {
      for (int c4 = 0; c4 < CK4; ++c4) {
        float4 sv = *(const float4*)(srow + ch * CK + c4 * 4);
        const float* qq = qch + c4 * 100 + i0 * 4;
#pragma unroll
        for (int r = 0; r < 13; ++r) {
          if (r < ni) {
            float4 qv = *(const float4*)(qq + r * 4);
            acc[r] = fmaf(qv.x, sv.x, acc[r]);
            acc[r] = fmaf(qv.y, sv.y, acc[r]);
            acc[r] = fmaf(qv.z, sv.z, acc[r]);
            acc[r] = fmaf(qv.w, sv.w, acc[r]);
          }
        }
      }
    }
  }
  __syncthreads();
  if (tid < 25) rinv[tid] = 1.f / (sqrtf(nsq[tid]) + EPSF);
  __syncthreads();
  if (half < 2) {
#pragma unroll
    for (int r = 0; r < 13; ++r)
      if (r < ni) S[(i0 + r) * 125 + s] = acc[r] * rinv[i0 + r];
  }
  __syncthreads();

  float* Tsq = qch;          // 25x125
  float* Tqs = qch + 3200;   // 125x25
  float* Bm  = qch + 6400;   // 25x25

  if (tid < 200) {           // T_sq: softmax over s, gamma=20; 8 lanes per row
    int i = tid >> 3, l = tid & 7;
    const float* Srow = S + i * 125;
    float mx = -1e30f;
    for (int ss = l; ss < 125; ss += 8) mx = fmaxf(mx, Srow[ss]);
    mx = fmaxf(mx, __shfl_xor(mx, 1, 8));
    mx = fmaxf(mx, __shfl_xor(mx, 2, 8));
    mx = fmaxf(mx, __shfl_xor(mx, 4, 8));
    float sm = 0.f;
    for (int ss = l; ss < 125; ss += 8) {
      float e = __expf(20.f * (Srow[ss] - mx));
      Tsq[i * 125 + ss] = e; sm += e;
    }
    sm += __shfl_xor(sm, 1, 8);
    sm += __shfl_xor(sm, 2, 8);
    sm += __shfl_xor(sm, 4, 8);
    float rs = 1.f / sm;
    for (int ss = l; ss < 125; ss += 8) Tsq[i * 125 + ss] *= rs;
  }
  if (tid < 125) {           // T_qs: softmax over i, gamma=10 (no barrier needed:
    int ss = tid;            //  reads S only, writes disjoint LDS)
    float mx = -1e30f;
#pragma unroll
    for (int i = 0; i < 25; ++i) mx = fmaxf(mx, S[i * 125 + ss]);
    float sm = 0.f;
#pragma unroll
    for (int i = 0; i < 25; ++i) {
      float e = __expf(10.f * (S[i * 125 + ss] - mx));
      Tqs[ss * 25 + i] = e; sm += e;
    }
    float rs = 1.f / sm;
#pragma unroll
    for (int i = 0; i < 25; ++i) Tqs[ss * 25 + i] *= rs;
  }
  __syncthreads();
  // B[i][i'] = sum_s Tqs[s][i] * Tsq[i'][s]
  for (int ii = tid; ii < 625; ii += 256) {
    int i = ii / 25, ip = ii % 25;
    float sum = 0.f;
    for (int ss = 0; ss < 125; ++ss)
      sum = fmaf(Tqs[ss * 25 + i], Tsq[ip * 125 + ss], sum);
    Bm[ii] = sum;
  }
  if (tid < 25) {            // rhs = 1 + 0.5 * colsum(Tqs)
    float c = 0.f;
    for (int ss = 0; ss < 125; ++ss) c += Tqs[ss * 25 + tid];
    rhs[tid] = 1.f + 0.5f * c;
    xv[tid] = rhs[tid];
  }
  __syncthreads();
  // (I - 0.25 B) x = rhs  via Neumann iteration, rho <= 0.25 -> 20 iters ~1e-12
  for (int it = 0; it < 20; ++it) {
    float nx = 0.f;
    if (tid < 25) {
      float sum = 0.f;
      const float* Br = Bm + tid * 25;
#pragma unroll
      for (int ip = 0; ip < 25; ++ip) sum = fmaf(Br[ip], xv[ip], sum);
      nx = rhs[tid] + 0.25f * sum;
    }
    __syncthreads();
    if (tid < 25) xv[tid] = nx;
    __syncthreads();
  }
  if (tid < 125) {           // katz_s (scale-free) -> per-class sums
    float kz = 0.f;
#pragma unroll
    for (int i = 0; i < 25; ++i) kz = fmaf(Tsq[i * 125 + tid], xv[i], kz);
    atomicAdd(&Pk[tid / 25], kz);
  }
  __syncthreads();
  if (tid == 0) {
    float den = Pk[0] + Pk[1] + Pk[2] + Pk[3] + Pk[4];
    int y = qy[n];
    float v = -(logf(Pk[y]) - logf(den)) * (1.0f / (float)NN);
    atomicAdd(out, v);
  }
}

extern "C" void kernel_launch(void* const* d_in, const int* in_sizes, int n_in,
                              void* d_out, int out_size, void* d_ws, size_t ws_size,
                              hipStream_t stream) {
  const float* sxf = (const float*)d_in[0];
  const float* qxf = (const float*)d_in[2];
  const int*   qy  = (const int*)d_in[3];
  float* out = (float*)d_out;
  float* supm = (float*)d_ws;   // 16*5*25*640 floats = 5.12 MB

  hipMemsetAsync(out, 0, sizeof(float), stream);
  kA1<<<80, 256, 0, stream>>>(sxf, supm);
  kA2<<<500, 256, 0, stream>>>(supm);
  kC<<<NN, 256, 0, stream>>>(qxf, qy, supm, out);
}

// Round 2
// 297.627 us; speedup vs baseline: 1.2127x; 1.2127x over previous
//
#include <hip/hip_runtime.h>
#include <hip/hip_bf16.h>
#include <math.h>

#define NN   1200
#define EPSF 1e-8f

typedef __attribute__((ext_vector_type(8)))  short bf8v;   // 8 bf16 = 4 VGPR
typedef __attribute__((ext_vector_type(16))) float f16v;   // 32x32 accum

static __device__ inline ushort f2bf(float v) {
  __hip_bfloat16 b = __float2bfloat16(v);
  return *reinterpret_cast<ushort*>(&b);
}
static __device__ inline float bf2f(ushort u) {
  union { unsigned x; float f; } c; c.x = ((unsigned)u) << 16; return c.f;
}

// ---- kA: mean over k_shot + L2-normalize + split to bf16 hi/lo -------------
// out layout: [b][hl][s][c] ushort, s = w*25 + j, plane stride 80000, b stride 160000
__global__ __launch_bounds__(256) void kA(const float* __restrict__ sxf,
                                          ushort* __restrict__ sup) {
  const int blk = blockIdx.x;            // b*5 + w
  const int b = blk / 5, w = blk % 5;
  const int tid = threadIdx.x;
  __shared__ __align__(16) float slab[25 * 641];   // [j][c] stride 641 (bank spread)
  __shared__ float rinv[25];
  const float* base = sxf + (size_t)blk * 5 * 16000;

  for (int f0 = tid * 4; f0 < 16000; f0 += 1024) {
    float4 a  = *(const float4*)(base + f0);
    float4 b1 = *(const float4*)(base + 16000 + f0);
    float4 c1 = *(const float4*)(base + 32000 + f0);
    float4 d1 = *(const float4*)(base + 48000 + f0);
    float4 e1 = *(const float4*)(base + 64000 + f0);
    float v[4];
    v[0] = (a.x + b1.x + c1.x + d1.x + e1.x) * 0.2f;
    v[1] = (a.y + b1.y + c1.y + d1.y + e1.y) * 0.2f;
    v[2] = (a.z + b1.z + c1.z + d1.z + e1.z) * 0.2f;
    v[3] = (a.w + b1.w + c1.w + d1.w + e1.w) * 0.2f;
#pragma unroll
    for (int u = 0; u < 4; ++u) {
      int f = f0 + u, j = f % 25, c = f / 25;   // input layout [c][hw]
      slab[j * 641 + c] = v[u];
    }
  }
  __syncthreads();
  if (tid < 200) {
    int i = tid >> 3, l = tid & 7;
    float ssq = 0.f;
    for (int c = l; c < 640; c += 8) { float v = slab[i * 641 + c]; ssq = fmaf(v, v, ssq); }
    ssq += __shfl_xor(ssq, 1, 8);
    ssq += __shfl_xor(ssq, 2, 8);
    ssq += __shfl_xor(ssq, 4, 8);
    if (l == 0) rinv[i] = 1.f / (sqrtf(ssq) + EPSF);
  }
  __syncthreads();
  for (int g0 = tid * 4; g0 < 16000; g0 += 1024) {
    int j = g0 / 640, c = g0 % 640;
    float r = rinv[j];
    ushort h[4], lo[4];
#pragma unroll
    for (int u = 0; u < 4; ++u) {
      float v = slab[j * 641 + c + u] * r;
      h[u] = f2bf(v);
      lo[u] = f2bf(v - bf2f(h[u]));
    }
    size_t o = (size_t)b * 160000 + (size_t)(w * 25 + j) * 640 + c;
    uint2 ph = { (unsigned)h[0] | ((unsigned)h[1] << 16), (unsigned)h[2] | ((unsigned)h[3] << 16) };
    uint2 pl = { (unsigned)lo[0] | ((unsigned)lo[1] << 16), (unsigned)lo[2] | ((unsigned)lo[3] << 16) };
    *(uint2*)(sup + o) = ph;
    *(uint2*)(sup + o + 80000) = pl;
  }
}

// ---- kC: split-bf16 MFMA GEMM + softmax + Katz + loss ----------------------
// LDS staging (bytes): Ah[32][72]bf16 @0 (4608), Al @4608, Bh[128][72] @9216,
// Bl @27648; total 46080. Post-GEMM aliases: Tsq[25][128]f32 @0, TqsT @12800,
// Bm[25][25] @25600, Sm[25][125] @30720.
__global__ __launch_bounds__(256, 3) void kC(const float* __restrict__ qxf,
                                             const int* __restrict__ qy,
                                             const ushort* __restrict__ sup,
                                             float* __restrict__ out) {
  const int n = blockIdx.x;
  const int b = n / 75;
  const int tid = threadIdx.x;
  const int lane = tid & 63;
  const int hi32 = lane >> 5;            // k-half within wave
  const int wv = tid >> 6;               // wave id = 32-col tile of S
  __shared__ __align__(16) char stage[46080];
  __shared__ float nsq[25], rinv[25], rhs[25], xv[25], Pk[5];

  const float* qb = qxf + (size_t)n * 16000;
  const ushort* supb = sup + (size_t)b * 160000;

  // zero staging (pad rows must be 0) + small arrays
  { unsigned* sd = (unsigned*)stage;
    for (int i = tid; i < 11520; i += 256) sd[i] = 0u; }
  if (tid < 25) nsq[tid] = 0.f;
  if (tid < 5)  Pk[tid] = 0.f;
  __syncthreads();

  f16v acc;
#pragma unroll
  for (int r = 0; r < 16; ++r) acc[r] = 0.f;
  const int arow = lane & 31;
  const int brow = wv * 32 + (lane & 31);

  for (int ch = 0; ch < 10; ++ch) {
    const int k0 = ch * 64;
    // stage A (query 25x64 fp32 -> hi/lo bf16) + norm accumulation
    for (int idx = tid; idx < 400; idx += 256) {
      int row = idx >> 4, c4 = idx & 15;
      float4 qv = *(const float4*)(qb + row * 640 + k0 + c4 * 4);
      atomicAdd(&nsq[row], qv.x*qv.x + qv.y*qv.y + qv.z*qv.z + qv.w*qv.w);
      ushort h[4], lo[4];
      float vv[4] = { qv.x, qv.y, qv.z, qv.w };
#pragma unroll
      for (int u = 0; u < 4; ++u) { h[u] = f2bf(vv[u]); lo[u] = f2bf(vv[u] - bf2f(h[u])); }
      uint2 ph = { (unsigned)h[0] | ((unsigned)h[1] << 16), (unsigned)h[2] | ((unsigned)h[3] << 16) };
      uint2 pl = { (unsigned)lo[0] | ((unsigned)lo[1] << 16), (unsigned)lo[2] | ((unsigned)lo[3] << 16) };
      *(uint2*)(stage + row * 144 + c4 * 8) = ph;
      *(uint2*)(stage + 4608 + row * 144 + c4 * 8) = pl;
    }
    // stage B (support hi/lo bf16, precomputed)
    for (int idx = tid; idx < 2000; idx += 256) {
      int hl = (idx >= 1000) ? 1 : 0;
      int r2 = idx - hl * 1000;
      int row = r2 >> 3, seg = r2 & 7;
      uint4 v = *(const uint4*)(supb + hl * 80000 + row * 640 + k0 + seg * 8);
      *(uint4*)(stage + 9216 + hl * 18432 + row * 144 + seg * 16) = v;
    }
    __syncthreads();
#pragma unroll
    for (int ks = 0; ks < 4; ++ks) {
      const int kb2 = ks * 32 + hi32 * 16;       // byte offset along k
      bf8v ah = *(const bf8v*)(stage + arow * 144 + kb2);
      bf8v al = *(const bf8v*)(stage + 4608 + arow * 144 + kb2);
      bf8v bh = *(const bf8v*)(stage + 9216 + brow * 144 + kb2);
      bf8v bl = *(const bf8v*)(stage + 27648 + brow * 144 + kb2);
      acc = __builtin_amdgcn_mfma_f32_32x32x16_bf16(ah, bh, acc, 0, 0, 0);
      acc = __builtin_amdgcn_mfma_f32_32x32x16_bf16(al, bh, acc, 0, 0, 0);
      acc = __builtin_amdgcn_mfma_f32_32x32x16_bf16(ah, bl, acc, 0, 0, 0);
    }
    __syncthreads();
  }

  if (tid < 25) rinv[tid] = 1.f / (sqrtf(nsq[tid]) + EPSF);
  __syncthreads();

  float* Sm = (float*)(stage + 30720);   // [25][125]
  { const int col = wv * 32 + (lane & 31);
#pragma unroll
    for (int r = 0; r < 16; ++r) {
      int row = (r & 3) + 8 * (r >> 2) + 4 * hi32;
      if (row < 25 && col < 125) Sm[row * 125 + col] = acc[r] * rinv[row];
    }
  }
  __syncthreads();

  float* Tsq  = (float*)stage;            // [25][128]
  float* TqsT = (float*)(stage + 12800);  // [25][128]
  float* Bm   = (float*)(stage + 25600);  // [25][25]

  if (tid < 200) {   // row softmax, gamma=20
    int i = tid >> 3, l = tid & 7;
    const float* Srow = Sm + i * 125;
    float mx = -1e30f;
    for (int ss = l; ss < 125; ss += 8) mx = fmaxf(mx, Srow[ss]);
    mx = fmaxf(mx, __shfl_xor(mx, 1, 8));
    mx = fmaxf(mx, __shfl_xor(mx, 2, 8));
    mx = fmaxf(mx, __shfl_xor(mx, 4, 8));
    float sm = 0.f;
    for (int ss = l; ss < 128; ss += 8) {
      float e = 0.f;
      if (ss < 125) { e = __expf(20.f * (Srow[ss] - mx)); sm += e; }
      Tsq[i * 128 + ss] = e;
    }
    sm += __shfl_xor(sm, 1, 8);
    sm += __shfl_xor(sm, 2, 8);
    sm += __shfl_xor(sm, 4, 8);
    float rs = 1.f / sm;
    for (int ss = l; ss < 125; ss += 8) Tsq[i * 128 + ss] *= rs;
  }
  if (tid < 125) {   // col softmax, gamma=10 -> transposed store [i][s]
    int ss = tid;
    float mx = -1e30f;
#pragma unroll
    for (int i = 0; i < 25; ++i) mx = fmaxf(mx, Sm[i * 125 + ss]);
    float sm = 0.f;
    float ev[25];
#pragma unroll
    for (int i = 0; i < 25; ++i) { ev[i] = __expf(10.f * (Sm[i * 125 + ss] - mx)); sm += ev[i]; }
    float rs = 1.f / sm;
#pragma unroll
    for (int i = 0; i < 25; ++i) TqsT[i * 128 + ss] = ev[i] * rs;
  }
  if (tid < 25) { TqsT[tid * 128 + 125] = 0.f; TqsT[tid * 128 + 126] = 0.f; TqsT[tid * 128 + 127] = 0.f; }
  __syncthreads();

  for (int ii = tid; ii < 625; ii += 256) {   // B = TqsT · Tsq^T (25x25, K=125)
    int i = ii / 25, ip = ii % 25;
    const float* ta = TqsT + i * 128;
    const float* tb = Tsq + ip * 128;
    float4 s4 = { 0.f, 0.f, 0.f, 0.f };
#pragma unroll
    for (int q4 = 0; q4 < 32; ++q4) {
      float4 a4 = *(const float4*)(ta + q4 * 4);
      float4 b4 = *(const float4*)(tb + q4 * 4);
      s4.x = fmaf(a4.x, b4.x, s4.x); s4.y = fmaf(a4.y, b4.y, s4.y);
      s4.z = fmaf(a4.z, b4.z, s4.z); s4.w = fmaf(a4.w, b4.w, s4.w);
    }
    Bm[i * 25 + ip] = (s4.x + s4.y) + (s4.z + s4.w);
  }
  if (tid < 25) {    // rhs = 1 + 0.5 * colsum(Tqs)
    const float* ta = TqsT + tid * 128;
    float4 s4 = { 0.f, 0.f, 0.f, 0.f };
#pragma unroll
    for (int q4 = 0; q4 < 32; ++q4) {
      float4 a4 = *(const float4*)(ta + q4 * 4);
      s4.x += a4.x; s4.y += a4.y; s4.z += a4.z; s4.w += a4.w;
    }
    rhs[tid] = 1.f + 0.5f * ((s4.x + s4.y) + (s4.z + s4.w));
  }
  __syncthreads();

  if (tid < 64) {    // Jacobi in wave 0, no barriers: x = rhs + 0.25 B x
    float Brow[25], x, rh;
    if (tid < 25) {
      rh = rhs[tid]; x = rh;
#pragma unroll
      for (int ip = 0; ip < 25; ++ip) Brow[ip] = Bm[tid * 25 + ip];
    } else {
      rh = 0.f; x = 0.f;
#pragma unroll
      for (int ip = 0; ip < 25; ++ip) Brow[ip] = 0.f;
    }
#pragma unroll
    for (int it = 0; it < 16; ++it) {
      float sum = 0.f;
#pragma unroll
      for (int ip = 0; ip < 25; ++ip) sum = fmaf(Brow[ip], __shfl(x, ip), sum);
      x = rh + 0.25f * sum;
    }
    if (tid < 25) xv[tid] = x;
  }
  __syncthreads();

  if (tid < 125) {   // katz_s (scale-free) -> class sums
    float kz = 0.f;
#pragma unroll
    for (int i = 0; i < 25; ++i) kz = fmaf(Tsq[i * 128 + tid], xv[i], kz);
    atomicAdd(&Pk[tid / 25], kz);
  }
  __syncthreads();
  if (tid == 0) {
    float den = Pk[0] + Pk[1] + Pk[2] + Pk[3] + Pk[4];
    int y = qy[n];
    float v = -(logf(Pk[y]) - logf(den)) * (1.0f / (float)NN);
    atomicAdd(out, v);
  }
}

extern "C" void kernel_launch(void* const* d_in, const int* in_sizes, int n_in,
                              void* d_out, int out_size, void* d_ws, size_t ws_size,
                              hipStream_t stream) {
  const float* sxf = (const float*)d_in[0];
  const float* qxf = (const float*)d_in[2];
  const int*   qy  = (const int*)d_in[3];
  float* out = (float*)d_out;
  ushort* sup = (ushort*)d_ws;   // 16*2*125*640 ushort = 5.12 MB

  hipMemsetAsync(out, 0, sizeof(float), stream);
  kA<<<80, 256, 0, stream>>>(sxf, sup);
  kC<<<NN, 256, 0, stream>>>(qxf, qy, sup, out);
}

// Round 3
// 251.486 us; speedup vs baseline: 1.4352x; 1.1835x over previous
//
#include <hip/hip_runtime.h>
#include <hip/hip_bf16.h>
#include <math.h>

#define NN   1200
#define EPSF 1e-8f

typedef __attribute__((ext_vector_type(8)))  short bf8v;
typedef __attribute__((ext_vector_type(16))) float f16v;

static __device__ inline ushort f2bf(float v) {
  __hip_bfloat16 b = __float2bfloat16(v);
  return *reinterpret_cast<ushort*>(&b);
}
static __device__ inline float bf2f(ushort u) {
  union { unsigned x; float f; } c; c.x = ((unsigned)u) << 16; return c.f;
}

// ---- kA1: mean over k_shot + transpose -> supmean[b*125+s][c] fp32 ---------
__global__ __launch_bounds__(256) void kA1(const float* __restrict__ sxf,
                                           float* __restrict__ supmean) {
  const int blk = blockIdx.x;                    // b*25 + w*5 + ck
  const int b = blk / 25, rem = blk % 25, w = rem / 5, ck = rem % 5;
  const int c0 = ck * 128;
  const int tid = threadIdx.x;
  __shared__ float lds[3200];                    // [c_local(128)][j(25)]
  const float* base = sxf + (size_t)(b * 25 + w * 5) * 16000 + (size_t)c0 * 25;

  for (int f0 = tid * 4; f0 < 3200; f0 += 1024) {
    float4 a  = *(const float4*)(base + f0);
    float4 b1 = *(const float4*)(base + 16000 + f0);
    float4 c1 = *(const float4*)(base + 32000 + f0);
    float4 d1 = *(const float4*)(base + 48000 + f0);
    float4 e1 = *(const float4*)(base + 64000 + f0);
    lds[f0 + 0] = (a.x + b1.x + c1.x + d1.x + e1.x) * 0.2f;
    lds[f0 + 1] = (a.y + b1.y + c1.y + d1.y + e1.y) * 0.2f;
    lds[f0 + 2] = (a.z + b1.z + c1.z + d1.z + e1.z) * 0.2f;
    lds[f0 + 3] = (a.w + b1.w + c1.w + d1.w + e1.w) * 0.2f;
  }
  __syncthreads();
  for (int g = tid; g < 3200; g += 256) {
    int j = g >> 7, cc = g & 127;
    supmean[(size_t)(b * 125 + w * 25 + j) * 640 + c0 + cc] = lds[cc * 25 + j];
  }
}

// ---- kA2: L2-normalize rows + split to bf16 hi/lo --------------------------
// sup layout: [b][hl][s][c] ushort; b stride 160000, hl stride 80000
__global__ __launch_bounds__(256) void kA2(const float* __restrict__ supmean,
                                           ushort* __restrict__ sup) {
  const int r = blockIdx.x * 4 + (threadIdx.x >> 6);    // 0..1999
  const int lane = threadIdx.x & 63;
  const int b = r / 125, s = r % 125;
  const float* row = supmean + (size_t)r * 640;
  float4 v0 = *(const float4*)(row + lane * 4);
  float4 v1 = *(const float4*)(row + 256 + lane * 4);
  float4 v2 = {0.f, 0.f, 0.f, 0.f};
  if (lane < 32) v2 = *(const float4*)(row + 512 + lane * 4);
  float ssq = v0.x*v0.x + v0.y*v0.y + v0.z*v0.z + v0.w*v0.w
            + v1.x*v1.x + v1.y*v1.y + v1.z*v1.z + v1.w*v1.w
            + v2.x*v2.x + v2.y*v2.y + v2.z*v2.z + v2.w*v2.w;
#pragma unroll
  for (int d = 32; d; d >>= 1) ssq += __shfl_xor(ssq, d);
  const float rinv = 1.f / (sqrtf(ssq) + EPSF);
  ushort* dst = sup + (size_t)b * 160000 + (size_t)s * 640;
#pragma unroll
  for (int seg = 0; seg < 3; ++seg) {
    if (seg == 2 && lane >= 32) break;
    float4 v = (seg == 0) ? v0 : ((seg == 1) ? v1 : v2);
    int c = seg * 256 + lane * 4;
    float vv[4] = { v.x * rinv, v.y * rinv, v.z * rinv, v.w * rinv };
    ushort h[4], lo[4];
#pragma unroll
    for (int u = 0; u < 4; ++u) { h[u] = f2bf(vv[u]); lo[u] = f2bf(vv[u] - bf2f(h[u])); }
    uint2 ph = { (unsigned)h[0] | ((unsigned)h[1] << 16), (unsigned)h[2] | ((unsigned)h[3] << 16) };
    uint2 pl = { (unsigned)lo[0] | ((unsigned)lo[1] << 16), (unsigned)lo[2] | ((unsigned)lo[3] << 16) };
    *(uint2*)(dst + c) = ph;
    *(uint2*)(dst + 80000 + c) = pl;
  }
}

// ---- kG: split-bf16 MFMA GEMM, 2 queries per block -> Sg[n][25][128] -------
// LDS: A0h@0 A0l@4096 A1h@8192 A1l@12288 (32x128B each), Bh@16384 Bl@32768
// (128x128B each); XOR swizzle byte ^= (row&7)<<4 on every 16B slot.
__global__ __launch_bounds__(256, 3) void kG(const float* __restrict__ qxf,
                                             const ushort* __restrict__ sup,
                                             float* __restrict__ Sg) {
  const int blk = blockIdx.x;                 // 16*38
  const int b = blk / 38, qq = blk - b * 38;
  const int q0 = 2 * qq;
  const int n0 = b * 75 + q0;
  const bool has1 = (q0 + 1) < 75;
  const int tid = threadIdx.x;
  const int lane = tid & 63, hi32 = lane >> 5, wv = tid >> 6;
  __shared__ __align__(16) char st[49152];
  __shared__ float nsq[64], rinvs[64];

  const float* qb0 = qxf + (size_t)n0 * 16000;
  const float* qb1 = qxf + (size_t)(n0 + (has1 ? 1 : 0)) * 16000;
  const ushort* supb = sup + (size_t)b * 160000;

  if (tid < 64) nsq[tid] = 0.f;
  __syncthreads();

  f16v acc0, acc1;
#pragma unroll
  for (int r = 0; r < 16; ++r) { acc0[r] = 0.f; acc1[r] = 0.f; }
  const int arow = lane & 31;
  const int brow = wv * 32 + (lane & 31);
  const int aoffs[4] = {
    (arow * 128 + 0 * 32 + hi32 * 16) ^ ((arow & 7) << 4),
    (arow * 128 + 1 * 32 + hi32 * 16) ^ ((arow & 7) << 4),
    (arow * 128 + 2 * 32 + hi32 * 16) ^ ((arow & 7) << 4),
    (arow * 128 + 3 * 32 + hi32 * 16) ^ ((arow & 7) << 4) };
  const int boffs[4] = {
    (brow * 128 + 0 * 32 + hi32 * 16) ^ ((brow & 7) << 4),
    (brow * 128 + 1 * 32 + hi32 * 16) ^ ((brow & 7) << 4),
    (brow * 128 + 2 * 32 + hi32 * 16) ^ ((brow & 7) << 4),
    (brow * 128 + 3 * 32 + hi32 * 16) ^ ((brow & 7) << 4) };

  for (int ch = 0; ch < 10; ++ch) {
    const int k0 = ch * 64;
    // A stage: 2 queries x 25 rows x 16 float4, + norm partials via shfl
    for (int idx = tid; idx < 800; idx += 256) {
      int qs = (idx >= 400) ? 1 : 0;
      int r2 = idx - qs * 400;
      int row = r2 >> 4, c4 = r2 & 15;
      const float* qb = qs ? qb1 : qb0;
      float4 qv = *(const float4*)(qb + row * 640 + k0 + c4 * 4);
      float ssq = qv.x*qv.x + qv.y*qv.y + qv.z*qv.z + qv.w*qv.w;
      ssq += __shfl_xor(ssq, 1, 16);
      ssq += __shfl_xor(ssq, 2, 16);
      ssq += __shfl_xor(ssq, 4, 16);
      ssq += __shfl_xor(ssq, 8, 16);
      ushort h[4], lo[4];
      float vv[4] = { qv.x, qv.y, qv.z, qv.w };
#pragma unroll
      for (int u = 0; u < 4; ++u) { h[u] = f2bf(vv[u]); lo[u] = f2bf(vv[u] - bf2f(h[u])); }
      uint2 ph = { (unsigned)h[0] | ((unsigned)h[1] << 16), (unsigned)h[2] | ((unsigned)h[3] << 16) };
      uint2 pl = { (unsigned)lo[0] | ((unsigned)lo[1] << 16), (unsigned)lo[2] | ((unsigned)lo[3] << 16) };
      int off = (row * 128 + c4 * 8) ^ ((row & 7) << 4);
      *(uint2*)(st + qs * 8192 + off) = ph;
      *(uint2*)(st + qs * 8192 + 4096 + off) = pl;
      if ((r2 & 15) == 0) nsq[qs * 32 + row] += ssq;   // unique writer per entry
    }
    // B stage: hi/lo planes, 125 rows x 8 uint4
    for (int idx = tid; idx < 2000; idx += 256) {
      int hl = (idx >= 1000) ? 1 : 0;
      int r2 = idx - hl * 1000;
      int row = r2 >> 3, seg = r2 & 7;
      uint4 v = *(const uint4*)(supb + hl * 80000 + row * 640 + k0 + seg * 8);
      int off = (row * 128 + seg * 16) ^ ((row & 7) << 4);
      *(uint4*)(st + 16384 + hl * 16384 + off) = v;
    }
    __syncthreads();
#pragma unroll
    for (int ks = 0; ks < 4; ++ks) {
      bf8v bh  = *(const bf8v*)(st + 16384 + boffs[ks]);
      bf8v bl  = *(const bf8v*)(st + 32768 + boffs[ks]);
      bf8v ah0 = *(const bf8v*)(st + aoffs[ks]);
      bf8v al0 = *(const bf8v*)(st + 4096 + aoffs[ks]);
      bf8v ah1 = *(const bf8v*)(st + 8192 + aoffs[ks]);
      bf8v al1 = *(const bf8v*)(st + 12288 + aoffs[ks]);
      acc0 = __builtin_amdgcn_mfma_f32_32x32x16_bf16(ah0, bh, acc0, 0, 0, 0);
      acc0 = __builtin_amdgcn_mfma_f32_32x32x16_bf16(al0, bh, acc0, 0, 0, 0);
      acc0 = __builtin_amdgcn_mfma_f32_32x32x16_bf16(ah0, bl, acc0, 0, 0, 0);
      acc1 = __builtin_amdgcn_mfma_f32_32x32x16_bf16(ah1, bh, acc1, 0, 0, 0);
      acc1 = __builtin_amdgcn_mfma_f32_32x32x16_bf16(al1, bh, acc1, 0, 0, 0);
      acc1 = __builtin_amdgcn_mfma_f32_32x32x16_bf16(ah1, bl, acc1, 0, 0, 0);
    }
    __syncthreads();
  }

  if (tid < 64) rinvs[tid] = 1.f / (sqrtf(nsq[tid]) + EPSF);
  __syncthreads();

  const int col = wv * 32 + (lane & 31);
  float* So0 = Sg + (size_t)n0 * 3200;
  float* So1 = So0 + 3200;
#pragma unroll
  for (int r = 0; r < 16; ++r) {
    int row = (r & 3) + 8 * (r >> 2) + 4 * hi32;
    if (row < 25) {
      So0[row * 128 + col] = acc0[r] * rinvs[row];
      if (has1) So1[row * 128 + col] = acc1[r] * rinvs[32 + row];
    }
  }
}

// ---- kT: softmaxes + B + Jacobi + katz + loss; LDS row stride 132 ----------
#define LD 132
__global__ __launch_bounds__(256, 4) void kT(const float* __restrict__ Sg,
                                             const int* __restrict__ qy,
                                             float* __restrict__ out) {
  const int n = blockIdx.x;
  const int tid = threadIdx.x;
  __shared__ __align__(16) float S[25 * LD];     // becomes Tsq in place
  __shared__ __align__(16) float TqsT[25 * LD];
  __shared__ float Bm[625], rhs[25], xv[25], Pk[5];

  const float* sgn = Sg + (size_t)n * 3200;
  for (int idx = tid; idx < 800; idx += 256) {
    int row = idx >> 5, q4 = idx & 31;
    *(float4*)(S + row * LD + q4 * 4) = *(const float4*)(sgn + row * 128 + q4 * 4);
  }
  if (tid < 5) Pk[tid] = 0.f;
  if (tid >= 32 && tid < 57) {                   // zero TqsT pad cols 125..127
    int i = tid - 32;
    TqsT[i * LD + 125] = 0.f; TqsT[i * LD + 126] = 0.f; TqsT[i * LD + 127] = 0.f;
  }
  __syncthreads();

  if (tid < 125) {                               // col softmax (gamma=10) -> TqsT
    float mx = -1e30f;
#pragma unroll
    for (int i = 0; i < 25; ++i) mx = fmaxf(mx, S[i * LD + tid]);
    float sm = 0.f;
#pragma unroll
    for (int i = 0; i < 25; ++i) {
      float e = __expf(10.f * (S[i * LD + tid] - mx));
      TqsT[i * LD + tid] = e; sm += e;
    }
    float rs = 1.f / sm;
#pragma unroll
    for (int i = 0; i < 25; ++i) TqsT[i * LD + tid] *= rs;
  }
  __syncthreads();
  if (tid < 200) {                               // row softmax (gamma=20) in place
    int i = tid >> 3, l = tid & 7;
    float* Srow = S + i * LD;
    float mx = -1e30f;
    for (int ss = l; ss < 125; ss += 8) mx = fmaxf(mx, Srow[ss]);
    mx = fmaxf(mx, __shfl_xor(mx, 1, 8));
    mx = fmaxf(mx, __shfl_xor(mx, 2, 8));
    mx = fmaxf(mx, __shfl_xor(mx, 4, 8));
    float sm = 0.f;
    for (int ss = l; ss < 128; ss += 8) {
      float e = 0.f;
      if (ss < 125) { e = __expf(20.f * (Srow[ss] - mx)); sm += e; }
      Srow[ss] = e;
    }
    sm += __shfl_xor(sm, 1, 8);
    sm += __shfl_xor(sm, 2, 8);
    sm += __shfl_xor(sm, 4, 8);
    float rs = 1.f / sm;
    for (int ss = l; ss < 125; ss += 8) Srow[ss] *= rs;
  }
  __syncthreads();

  for (int ii = tid; ii < 625; ii += 256) {      // B = TqsT . Tsq^T (K=125)
    int i = ii / 25, ip = ii % 25;
    const float* ta = TqsT + i * LD;
    const float* tb = S + ip * LD;
    float4 s4 = { 0.f, 0.f, 0.f, 0.f };
#pragma unroll
    for (int q4 = 0; q4 < 32; ++q4) {
      float4 a4 = *(const float4*)(ta + q4 * 4);
      float4 b4 = *(const float4*)(tb + q4 * 4);
      s4.x = fmaf(a4.x, b4.x, s4.x); s4.y = fmaf(a4.y, b4.y, s4.y);
      s4.z = fmaf(a4.z, b4.z, s4.z); s4.w = fmaf(a4.w, b4.w, s4.w);
    }
    Bm[ii] = (s4.x + s4.y) + (s4.z + s4.w);
  }
  if (tid < 25) {                                // rhs = 1 + 0.5*colsum(Tqs)
    const float* ta = TqsT + tid * LD;
    float4 s4 = { 0.f, 0.f, 0.f, 0.f };
#pragma unroll
    for (int q4 = 0; q4 < 32; ++q4) {
      float4 a4 = *(const float4*)(ta + q4 * 4);
      s4.x += a4.x; s4.y += a4.y; s4.z += a4.z; s4.w += a4.w;
    }
    rhs[tid] = 1.f + 0.5f * ((s4.x + s4.y) + (s4.z + s4.w));
  }
  __syncthreads();

  if (tid < 64) {                                // Jacobi, wave 0, 16 iters
    float Brow[25], x, rh;
    if (tid < 25) {
      rh = rhs[tid]; x = rh;
#pragma unroll
      for (int ip = 0; ip < 25; ++ip) Brow[ip] = Bm[tid * 25 + ip];
    } else {
      rh = 0.f; x = 0.f;
#pragma unroll
      for (int ip = 0; ip < 25; ++ip) Brow[ip] = 0.f;
    }
#pragma unroll
    for (int it = 0; it < 16; ++it) {
      float sum = 0.f;
#pragma unroll
      for (int ip = 0; ip < 25; ++ip) sum = fmaf(Brow[ip], __shfl(x, ip), sum);
      x = rh + 0.25f * sum;
    }
    if (tid < 25) xv[tid] = x;
  }
  __syncthreads();

  if (tid < 125) {                               // katz -> class sums
    float kz = 0.f;
#pragma unroll
    for (int i = 0; i < 25; ++i) kz = fmaf(S[i * LD + tid], xv[i], kz);
    atomicAdd(&Pk[tid / 25], kz);
  }
  __syncthreads();
  if (tid == 0) {
    float den = Pk[0] + Pk[1] + Pk[2] + Pk[3] + Pk[4];
    int y = qy[n];
    float v = -(logf(Pk[y]) - logf(den)) * (1.0f / (float)NN);
    atomicAdd(out, v);
  }
}

extern "C" void kernel_launch(void* const* d_in, const int* in_sizes, int n_in,
                              void* d_out, int out_size, void* d_ws, size_t ws_size,
                              hipStream_t stream) {
  const float* sxf = (const float*)d_in[0];
  const float* qxf = (const float*)d_in[2];
  const int*   qy  = (const int*)d_in[3];
  float* out = (float*)d_out;
  float*  supmean = (float*)d_ws;                        // 5.12 MB
  ushort* sup     = (ushort*)((char*)d_ws + 5120000);    // 5.12 MB
  float*  Sgw     = (float*)((char*)d_ws + 10240000);    // 15.36 MB

  hipMemsetAsync(out, 0, sizeof(float), stream);
  kA1<<<400, 256, 0, stream>>>(sxf, supmean);
  kA2<<<500, 256, 0, stream>>>(supmean, sup);
  kG<<<608, 256, 0, stream>>>(qxf, sup, Sgw);
  kT<<<NN, 256, 0, stream>>>(Sgw, qy, out);
}